// Round 9
// baseline (89961.652 us; speedup 1.0000x reference)
//
#include <hip/hip_runtime.h>

#define VV    32000
#define EE    256
#define RSZ   1024
#define BB    64
#define TT    2048
#define NGRP  3
#define EPSLN 1e-5f

#define NBLK_PER_GRP 64
#define NBLK  (NBLK_PER_GRP * NGRP)   // 192 blocks
#define NTHR  512                     // 8 waves
#define SLAB  (BB * RSZ)

#define BAR_OFF (NGRP * 2 * SLAB)     // floats offset of barrier words in d_ws

// LDS float layout: [0, 32768) weights [k][16]; [32768, +3*2048) act chunk bufs
#define WOFF   0
#define STAGE  (2048 * 16)
#define CHUNKF (64 * 32)
#define SMEMF  (STAGE + 3 * CHUNKF)   // 38912 floats = 152 KB

typedef __attribute__((address_space(1))) const void gas_cvoid;
typedef __attribute__((address_space(3))) void las_void;

#define SCHED_FENCE() asm volatile("" ::: "memory")

__global__ __launch_bounds__(NTHR, 2)
void reservoir_main(const int*   __restrict__ x,        // [B,T]
                    const float* __restrict__ embed_w,  // [V,E]
                    const float* __restrict__ Win0,
                    const float* __restrict__ Win1,
                    const float* __restrict__ Win2,
                    const float* __restrict__ Rm0,
                    const float* __restrict__ Rm1,
                    const float* __restrict__ Rm2,
                    const float* __restrict__ ln_w,
                    const float* __restrict__ ln_b,
                    float*       __restrict__ states,
                    unsigned*    __restrict__ bar,
                    float*       __restrict__ out)
{
    const int blk  = blockIdx.x;
    const int grp  = blk >> 6;               // layer
    const int gb   = blk & 63;
    const int c0   = gb << 4;                // 16-col slice
    const int tid  = threadIdx.x;
    const int wv   = tid >> 6;               // wave 0..7
    const int lane = tid & 63;
    const int kg   = wv & 3;                 // k quarter (8 floats of each 32-chunk)
    const int rh   = wv >> 2;                // row half
    const int row0 = (rh << 5) + ((lane >> 2) << 1);  // even row, 2 rows/lane
    const int row1 = row0 + 1;
    const int cg4  = (lane & 3) << 2;        // col quad
    const int sw0  = (row0 >> 1) & 7;        // read-side swizzle keys
    const int sw1  = (row1 >> 1) & 7;

    // staging identity: this lane DMAs row srow, float4-slot sko (k pre-swizzled)
    const int srow = (wv << 3) + (lane >> 3);      // 0..63
    const int sko  = lane & 7;
    const int sswz = ((sko ^ ((srow >> 1) & 7)) << 2);   // float offset within 32

    const float* Wl = (grp == 0) ? Win0 : ((grp == 1) ? Win1 : Win2);
    const float* Rl = (grp == 0) ? Rm0  : ((grp == 1) ? Rm1  : Rm2);
    const int Kw    = (grp == 0) ? EE : RSZ;
    const int nCh   = 32 + (Kw >> 5);        // 40 (layer0) or 64

    __shared__ float smem[SMEMF];

    // ---- stage weights to LDS once: [k][16] ----
    for (int i = tid; i < RSZ * 16; i += NTHR) {
        const int k = i >> 4, c = i & 15;
        smem[WOFF + i] = Rl[(size_t)k * RSZ + c0 + c];
    }
    for (int i = tid; i < Kw * 16; i += NTHR) {
        const int k = i >> 4, c = i & 15;
        smem[WOFF + RSZ * 16 + i] = Wl[(size_t)k * RSZ + c0 + c];
    }
    __syncthreads();

    unsigned* leaf  = bar;                   // leaf i at bar[i*16]
    unsigned* root  = bar + 128;
    unsigned* epoch = bar + 160;

    float* const sl = states + (size_t)grp * 2 * SLAB;

    for (int tick = 0; tick < TT + NGRP - 1; ++tick) {
        const int t = tick - grp;            // uniform per block
        if (0 <= t && t < TT) {
            const float* sprev = sl + (size_t)((t + 1) & 1) * SLAB;
            const float* gR = sprev + (size_t)srow * RSZ + sswz;
            const float* gW;
            if (grp == 0) {
                const int tok = x[srow * TT + t];
                gW = embed_w + (size_t)tok * EE + sswz;
            } else {
                gW = states + ((size_t)(grp - 1) * 2 + (t & 1)) * SLAB
                     + (size_t)srow * RSZ + sswz;
            }
            // retire token load so vmcnt counting below sees only DMA ops
            asm volatile("s_waitcnt vmcnt(0)" ::: "memory");

            float acc[2][4] = {{0.f,0.f,0.f,0.f},{0.f,0.f,0.f,0.f}};

            auto ISSUE = [&](int c) {
                const float* g = (c < 32) ? (gR + (c << 5)) : (gW + ((c - 32) << 5));
                float* l = &smem[STAGE + (c % 3) * CHUNKF + (wv << 8)];
                __builtin_amdgcn_global_load_lds((gas_cvoid*)g, (las_void*)l, 16, 0, 0);
            };
            auto COMPUTE = [&](int c) {
                const int sb = STAGE + (c % 3) * CHUNKF;
                const int wk = (c < 32) ? (c << 5) : (RSZ + ((c - 32) << 5));
                const int wb = WOFF + (wk + (kg << 3)) * 16 + cg4;
#pragma unroll
                for (int s = 0; s < 2; ++s) {
                    const int kol = (kg << 1) + s;
                    const float4 a0 = *(const float4*)&smem[sb + row0 * 32 + ((kol ^ sw0) << 2)];
                    const float4 a1 = *(const float4*)&smem[sb + row1 * 32 + ((kol ^ sw1) << 2)];
#pragma unroll
                    for (int j = 0; j < 4; ++j) {
                        const float4 w = *(const float4*)&smem[wb + ((s << 2) + j) * 16];
                        const float e0 = ((const float*)&a0)[j];
                        const float e1 = ((const float*)&a1)[j];
                        acc[0][0] = fmaf(e0, w.x, acc[0][0]);
                        acc[0][1] = fmaf(e0, w.y, acc[0][1]);
                        acc[0][2] = fmaf(e0, w.z, acc[0][2]);
                        acc[0][3] = fmaf(e0, w.w, acc[0][3]);
                        acc[1][0] = fmaf(e1, w.x, acc[1][0]);
                        acc[1][1] = fmaf(e1, w.y, acc[1][1]);
                        acc[1][2] = fmaf(e1, w.z, acc[1][2]);
                        acc[1][3] = fmaf(e1, w.w, acc[1][3]);
                    }
                }
            };

            // prologue: chunks 0,1 in flight; wait chunk0
            ISSUE(0);
            ISSUE(1);
            asm volatile("s_waitcnt vmcnt(1)" ::: "memory");
            __builtin_amdgcn_s_barrier();
            SCHED_FENCE();

            // main: invariant entering phase c: only chunk c+1 outstanding
            for (int c = 0; c < nCh; ++c) {
                if (c + 2 < nCh) ISSUE(c + 2);
                COMPUTE(c);
                if (c + 2 < nCh) {
                    asm volatile("s_waitcnt vmcnt(1)" ::: "memory");
                } else if (c + 1 < nCh) {
                    asm volatile("s_waitcnt vmcnt(0)" ::: "memory");
                }
                __builtin_amdgcn_s_barrier();
                SCHED_FENCE();
            }

            // ---- reduce over 4 k-groups via pbuf overlay on stage bufs ----
            float* sout = sl + (size_t)(t & 1) * SLAB;

            if (wv < 4) {                    // rh==0: rows 0..31, kg = wv
                *(float4*)&smem[STAGE + ((kg << 5) + row0) * 20 + (cg4 ^ ((row0 & 3) << 2))]
                    = make_float4(acc[0][0], acc[0][1], acc[0][2], acc[0][3]);
                *(float4*)&smem[STAGE + ((kg << 5) + row1) * 20 + (cg4 ^ ((row1 & 3) << 2))]
                    = make_float4(acc[1][0], acc[1][1], acc[1][2], acc[1][3]);
            }
            __syncthreads();
            {
                const int row = tid >> 4, col = tid & 15;
                const int cw  = (((col & 12) ^ ((row & 3) << 2)) | (col & 3));
                float s = 0.f;
#pragma unroll
                for (int g = 0; g < 4; ++g) s += smem[STAGE + ((g << 5) + row) * 20 + cw];
                sout[(size_t)row * RSZ + c0 + col] = tanhf(s);
            }
            __syncthreads();
            if (wv >= 4) {                   // rh==1: rows 32..63
                const int rl0 = row0 & 31, rl1 = row1 & 31;
                *(float4*)&smem[STAGE + ((kg << 5) + rl0) * 20 + (cg4 ^ ((rl0 & 3) << 2))]
                    = make_float4(acc[0][0], acc[0][1], acc[0][2], acc[0][3]);
                *(float4*)&smem[STAGE + ((kg << 5) + rl1) * 20 + (cg4 ^ ((rl1 & 3) << 2))]
                    = make_float4(acc[1][0], acc[1][1], acc[1][2], acc[1][3]);
            }
            __syncthreads();
            {
                const int rl = tid >> 4, col = tid & 15;
                const int cw = (((col & 12) ^ ((rl & 3) << 2)) | (col & 3));
                float s = 0.f;
#pragma unroll
                for (int g = 0; g < 4; ++g) s += smem[STAGE + ((g << 5) + rl) * 20 + cw];
                sout[(size_t)(32 + rl) * RSZ + c0 + col] = tanhf(s);
            }
        }

        // ---- hierarchical device barrier (monotonic epoch) ----
        __syncthreads();
        if (tid == 0) {
            __threadfence();                 // release
            const unsigned target = (unsigned)(tick + 1);
            unsigned prev = atomicAdd(&leaf[(blk & 7) << 4], 1u);
            if (prev == 24u * target - 1u) { // last of this leaf
                prev = atomicAdd(root, 1u);
                if (prev == 8u * target - 1u)
                    __hip_atomic_store(epoch, target, __ATOMIC_RELEASE,
                                       __HIP_MEMORY_SCOPE_AGENT);
            }
            while (__hip_atomic_load(epoch, __ATOMIC_RELAXED,
                                     __HIP_MEMORY_SCOPE_AGENT) < target)
                __builtin_amdgcn_s_sleep(2);
            __threadfence();                 // acquire
        }
        __syncthreads();
    }

    // ---- LayerNorm over h = s_2(T-1) (slot 1), blocks 0..63, 2 elems/thread ----
    if (blk < BB) {
        const float* h = states + ((size_t)2 * 2 + 1) * SLAB + (size_t)blk * RSZ;
        float* red = &smem[STAGE];

        const float hv0 = h[tid];
        const float hv1 = h[tid + 512];
        float v = hv0 + hv1;
#pragma unroll
        for (int o = 32; o > 0; o >>= 1) v += __shfl_down(v, o, 64);
        if ((tid & 63) == 0) red[tid >> 6] = v;
        __syncthreads();
        if (tid == 0) {
            float s = 0.f;
#pragma unroll
            for (int i = 0; i < 8; ++i) s += red[i];
            red[20] = s / (float)RSZ;
        }
        __syncthreads();
        const float mu = red[20];
        const float d0 = hv0 - mu, d1 = hv1 - mu;
        v = d0 * d0 + d1 * d1;
#pragma unroll
        for (int o = 32; o > 0; o >>= 1) v += __shfl_down(v, o, 64);
        __syncthreads();
        if ((tid & 63) == 0) red[tid >> 6] = v;
        __syncthreads();
        if (tid == 0) {
            float s = 0.f;
#pragma unroll
            for (int i = 0; i < 8; ++i) s += red[i];
            red[21] = rsqrtf(s / (float)RSZ + EPSLN);
        }
        __syncthreads();
        const float inv = red[21];
        out[blk * RSZ + tid]       = d0 * inv * ln_w[tid]       + ln_b[tid];
        out[blk * RSZ + tid + 512] = d1 * inv * ln_w[tid + 512] + ln_b[tid + 512];
    }
}

extern "C" void kernel_launch(void* const* d_in, const int* in_sizes, int n_in,
                              void* d_out, int out_size, void* d_ws, size_t ws_size,
                              hipStream_t stream) {
    const int*   x       = (const int*)  d_in[0];
    const float* embed_w = (const float*)d_in[1];
    const float* Win0    = (const float*)d_in[2];
    const float* Win1    = (const float*)d_in[3];
    const float* Win2    = (const float*)d_in[4];
    const float* Rm0     = (const float*)d_in[5];
    const float* Rm1     = (const float*)d_in[6];
    const float* Rm2     = (const float*)d_in[7];
    const float* ln_w    = (const float*)d_in[8];
    const float* ln_b    = (const float*)d_in[9];
    float*       out     = (float*)d_out;
    float*       states  = (float*)d_ws;
    unsigned*    bar     = (unsigned*)((float*)d_ws + BAR_OFF);

    hipMemsetAsync(d_ws, 0, (size_t)BAR_OFF * sizeof(float) + 4096, stream);

    void* args[] = {
        (void*)&x, (void*)&embed_w,
        (void*)&Win0, (void*)&Win1, (void*)&Win2,
        (void*)&Rm0, (void*)&Rm1, (void*)&Rm2,
        (void*)&ln_w, (void*)&ln_b,
        (void*)&states, (void*)&bar, (void*)&out
    };
    hipLaunchCooperativeKernel(reinterpret_cast<void*>(reservoir_main),
                               dim3(NBLK), dim3(NTHR), args, 0, stream);
}

// Round 10
// 63820.782 us; speedup vs baseline: 1.4096x; 1.4096x over previous
//
#include <hip/hip_runtime.h>

#define VV    32000
#define EE    256
#define RSZ   1024
#define BB    64
#define TT    2048
#define NGRP  3
#define EPSLN 1e-5f

#define NBLK_PER_GRP 64
#define NBLK  (NBLK_PER_GRP * NGRP)   // 192 blocks
#define NTHR  512                     // 8 waves = 16 k-groups x 32 threads
#define SLAB  (BB * RSZ)

#define BAR_OFF (NGRP * 2 * SLAB)     // floats offset of barrier words in d_ws

// one k-step (4 k's): 8 rows x 4 cols = 128 FMAs per 4 weight ds_read_b128
__device__ __forceinline__ void fma_step8x4(const float4 (&b)[8], const float* wrow,
                                            float (&acc)[8][4]) {
#pragma unroll
    for (int j = 0; j < 4; ++j) {
        const float4 w = *reinterpret_cast<const float4*>(wrow + j * 16);
#pragma unroll
        for (int r = 0; r < 8; ++r) {
            const float a = reinterpret_cast<const float*>(&b[r])[j];
            acc[r][0] = fmaf(a, w.x, acc[r][0]);
            acc[r][1] = fmaf(a, w.y, acc[r][1]);
            acc[r][2] = fmaf(a, w.z, acc[r][2]);
            acc[r][3] = fmaf(a, w.w, acc[r][3]);
        }
    }
}

__device__ __forceinline__ void ld8(float4 (&b)[8], const float* const (&p)[8],
                                    int off) {
#pragma unroll
    for (int r = 0; r < 8; ++r)
        b[r] = *reinterpret_cast<const float4*>(p[r] + off);
}

// NSTEPS (even) k-steps; named A/B double-buffer, rolled 2-step loop
template<int NSTEPS>
__device__ __forceinline__ void dot8(const float* const (&p)[8],
                                     const float* w, float (&acc)[8][4]) {
    float4 A[8], B[8];
    ld8(A, p, 0);
    ld8(B, p, 4);
    for (int j = 0; j < NSTEPS - 2; j += 2) {
        fma_step8x4(A, w + j * 64, acc);
        ld8(A, p, (j + 2) * 4);
        fma_step8x4(B, w + (j + 1) * 64, acc);
        ld8(B, p, (j + 3) * 4);
    }
    fma_step8x4(A, w + (NSTEPS - 2) * 64, acc);
    fma_step8x4(B, w + (NSTEPS - 1) * 64, acc);
}

__global__ __launch_bounds__(NTHR, 1)
void reservoir_main(const int*   __restrict__ x,        // [B,T]
                    const float* __restrict__ embed_w,  // [V,E]
                    const float* __restrict__ Win0,
                    const float* __restrict__ Win1,
                    const float* __restrict__ Win2,
                    const float* __restrict__ Rm0,
                    const float* __restrict__ Rm1,
                    const float* __restrict__ Rm2,
                    const float* __restrict__ ln_w,
                    const float* __restrict__ ln_b,
                    float*       __restrict__ states,
                    unsigned*    __restrict__ bar,
                    float*       __restrict__ out)
{
    const int blk   = blockIdx.x;
    const int grp   = blk >> 6;              // layer
    const int gb    = blk & 63;
    const int c0    = gb << 4;               // 16-col slice
    const int tid   = threadIdx.x;
    const int kg    = tid >> 5;              // 0..15 (k-groups of 32 threads)
    const int idx   = tid & 31;
    const int rbase = (idx >> 2) << 3;       // 8 rows/thread: 0,8,...,56
    const int cg4   = (idx & 3) << 2;        // col quad
    const int ph    = rbase >> 4;            // reduce write-phase 0..3

    const float* Wl  = (grp == 0) ? Win0 : ((grp == 1) ? Win1 : Win2);
    const float* Rl  = (grp == 0) ? Rm0  : ((grp == 1) ? Rm1  : Rm2);
    const int    Kw  = (grp == 0) ? EE : RSZ;
    const int    KwS = Kw >> 4;              // per-kg input k-slice (16 or 64)

    __shared__ float wlds[2048 * 16];        // 128 KB weight slab [k][16]
    __shared__ float pbuf[16][16][20];       // 20 KB partials (padded+swizzled)

    for (int i = tid; i < RSZ * 16; i += NTHR) {
        const int k = i >> 4, c = i & 15;
        wlds[i] = Rl[(size_t)k * RSZ + c0 + c];
    }
    for (int i = tid; i < Kw * 16; i += NTHR) {
        const int k = i >> 4, c = i & 15;
        wlds[RSZ * 16 + i] = Wl[(size_t)k * RSZ + c0 + c];
    }
    __syncthreads();

    // hierarchical barrier storage: 8 leaf lines + root + epoch
    unsigned* leaf  = bar;
    unsigned* root  = bar + 128;
    unsigned* epoch = bar + 160;

    float* const sl = states + (size_t)grp * 2 * SLAB;
    const float* const wRb = wlds + (kg << 6) * 16 + cg4;            // R: k-slice 64
    const float* const wWb = wlds + (RSZ + kg * KwS) * 16 + cg4;

    int xidx[8];
    if (grp == 0) {
#pragma unroll
        for (int r = 0; r < 8; ++r) xidx[r] = x[(rbase + r) * TT + 0];
    }

    for (int tick = 0; tick < TT + NGRP - 1; ++tick) {
        const int t = tick - grp;            // uniform per block
        if (0 <= t && t < TT) {
            const float* sprev = sl + (size_t)((t + 1) & 1) * SLAB;

            float acc[8][4];
#pragma unroll
            for (int r = 0; r < 8; ++r)
#pragma unroll
                for (int c = 0; c < 4; ++c) acc[r][c] = 0.f;

            {   // recurrent: s_prev @ R_l, k in [kg*64, kg*64+64) -> 16 ksteps
                const float* aR[8];
#pragma unroll
                for (int r = 0; r < 8; ++r)
                    aR[r] = sprev + (size_t)(rbase + r) * RSZ + (kg << 6);
                dot8<16>(aR, wRb, acc);
            }
            {   // input: cur @ W_l, k in [kg*KwS, +KwS) -> 4 or 16 ksteps
                const float* aW[8];
                if (grp == 0) {
#pragma unroll
                    for (int r = 0; r < 8; ++r)
                        aW[r] = embed_w + (size_t)xidx[r] * EE + kg * KwS;
                    dot8<4>(aW, wWb, acc);
                } else {
                    const float* cb = states + ((size_t)(grp - 1) * 2 + (t & 1)) * SLAB;
#pragma unroll
                    for (int r = 0; r < 8; ++r)
                        aW[r] = cb + (size_t)(rbase + r) * RSZ + kg * KwS;
                    dot8<16>(aW, wWb, acc);
                }
            }

            // prefetch next tick's token indices (layer 0 only)
            if (grp == 0 && t + 1 < TT) {
#pragma unroll
                for (int r = 0; r < 8; ++r) xidx[r] = x[(rbase + r) * TT + t + 1];
            }

            // ---- reduce over 16 k-groups, 4 row-quarter phases ----
            float* sout = sl + (size_t)(t & 1) * SLAB;
#pragma unroll
            for (int p = 0; p < 4; ++p) {
                if (ph == p) {
#pragma unroll
                    for (int r = 0; r < 8; ++r) {
                        const int lr = (rbase + r) & 15;
                        *reinterpret_cast<float4*>(
                            &pbuf[kg][lr][cg4 ^ ((lr & 3) << 2)])
                            = make_float4(acc[r][0], acc[r][1], acc[r][2], acc[r][3]);
                    }
                }
                __syncthreads();
                if (tid < 256) {
                    const int rl = tid >> 4, col = tid & 15;
                    const int cw = ((col & 12) ^ ((rl & 3) << 2)) | (col & 3);
                    float s = 0.f;
#pragma unroll
                    for (int g = 0; g < 16; ++g) s += pbuf[g][rl][cw];
                    sout[(size_t)(16 * p + rl) * RSZ + c0 + col] = tanhf(s);
                }
                __syncthreads();
            }
        }

        // ---- hierarchical device barrier (monotonic epoch) ----
        __syncthreads();
        if (tid == 0) {
            __threadfence();                 // release
            const unsigned target = (unsigned)(tick + 1);
            unsigned prev = atomicAdd(&leaf[(blk & 7) << 4], 1u);
            if (prev == 24u * target - 1u) { // last of this leaf
                prev = atomicAdd(root, 1u);
                if (prev == 8u * target - 1u)
                    __hip_atomic_store(epoch, target, __ATOMIC_RELEASE,
                                       __HIP_MEMORY_SCOPE_AGENT);
            }
            while (__hip_atomic_load(epoch, __ATOMIC_RELAXED,
                                     __HIP_MEMORY_SCOPE_AGENT) < target)
                __builtin_amdgcn_s_sleep(2);
            __threadfence();                 // acquire
        }
        __syncthreads();
    }

    // ---- LayerNorm over h = s_2(T-1) (slot 1), blocks 0..63, 2 elems/thread ----
    if (blk < BB) {
        const float* h = states + ((size_t)2 * 2 + 1) * SLAB + (size_t)blk * RSZ;
        float* red = &pbuf[0][0][0];

        const float hv0 = h[tid];
        const float hv1 = h[tid + 512];
        float v = hv0 + hv1;
#pragma unroll
        for (int o = 32; o > 0; o >>= 1) v += __shfl_down(v, o, 64);
        if ((tid & 63) == 0) red[tid >> 6] = v;
        __syncthreads();
        if (tid == 0) {
            float s = 0.f;
#pragma unroll
            for (int i = 0; i < 8; ++i) s += red[i];
            red[20] = s / (float)RSZ;
        }
        __syncthreads();
        const float mu = red[20];
        const float d0 = hv0 - mu, d1 = hv1 - mu;
        v = d0 * d0 + d1 * d1;
#pragma unroll
        for (int o = 32; o > 0; o >>= 1) v += __shfl_down(v, o, 64);
        __syncthreads();
        if ((tid & 63) == 0) red[tid >> 6] = v;
        __syncthreads();
        if (tid == 0) {
            float s = 0.f;
#pragma unroll
            for (int i = 0; i < 8; ++i) s += red[i];
            red[21] = rsqrtf(s / (float)RSZ + EPSLN);
        }
        __syncthreads();
        const float inv = red[21];
        out[blk * RSZ + tid]       = d0 * inv * ln_w[tid]       + ln_b[tid];
        out[blk * RSZ + tid + 512] = d1 * inv * ln_w[tid + 512] + ln_b[tid + 512];
    }
}

extern "C" void kernel_launch(void* const* d_in, const int* in_sizes, int n_in,
                              void* d_out, int out_size, void* d_ws, size_t ws_size,
                              hipStream_t stream) {
    const int*   x       = (const int*)  d_in[0];
    const float* embed_w = (const float*)d_in[1];
    const float* Win0    = (const float*)d_in[2];
    const float* Win1    = (const float*)d_in[3];
    const float* Win2    = (const float*)d_in[4];
    const float* Rm0     = (const float*)d_in[5];
    const float* Rm1     = (const float*)d_in[6];
    const float* Rm2     = (const float*)d_in[7];
    const float* ln_w    = (const float*)d_in[8];
    const float* ln_b    = (const float*)d_in[9];
    float*       out     = (float*)d_out;
    float*       states  = (float*)d_ws;
    unsigned*    bar     = (unsigned*)((float*)d_ws + BAR_OFF);

    hipMemsetAsync(d_ws, 0, (size_t)BAR_OFF * sizeof(float) + 4096, stream);

    void* args[] = {
        (void*)&x, (void*)&embed_w,
        (void*)&Win0, (void*)&Win1, (void*)&Win2,
        (void*)&Rm0, (void*)&Rm1, (void*)&Rm2,
        (void*)&ln_w, (void*)&ln_b,
        (void*)&states, (void*)&bar, (void*)&out
    };
    hipLaunchCooperativeKernel(reinterpret_cast<void*>(reservoir_main),
                               dim3(NBLK), dim3(NTHR), args, 0, stream);
}